// Round 9
// baseline (556.748 us; speedup 1.0000x reference)
//
#include <hip/hip_runtime.h>
#include <math.h>

#define NN 4096
#define F_IN 512
#define HEADS 8
#define D_HEAD 8
#define C1 64
#define NCLASS 16
#define MAX_DEG 128
#define LEAKY 0.2f
#define NBLK 1024

// Device-scope grid barrier: counters zeroed by k_init each launch.
__device__ __forceinline__ void grid_barrier(int* bar) {
    __syncthreads();
    if (threadIdx.x == 0) {
        __threadfence();  // release prior writes to device scope
        __hip_atomic_fetch_add(bar, 1, __ATOMIC_ACQ_REL, __HIP_MEMORY_SCOPE_AGENT);
        while (__hip_atomic_load(bar, __ATOMIC_ACQUIRE, __HIP_MEMORY_SCOPE_AGENT) < NBLK)
            __builtin_amdgcn_s_sleep(2);
    }
    __syncthreads();
}

__global__ __launch_bounds__(64) void k_init(int* __restrict__ bars) {
    if (threadIdx.x < 8) bars[threadIdx.x] = 0;
}

// One fused kernel, 1024 blocks x 256 threads (4 blocks/CU -> all co-resident).
// Phase 0: Wt transpose + CSR build (4 adj rows/block)
// Phase 1: h1 = x@W1 + e_src/e_dst   (1 row/wave)
// Phase 2: layer-1 attention + ELU + W2 proj + e2 dots (4 nodes/block)
// Phase 3: layer-2 attention + log_softmax (1 node/wave)
__global__ __launch_bounds__(256, 4) void k_fused(
    const float* __restrict__ x, const float* __restrict__ adj,
    const float* __restrict__ W1, const float* __restrict__ a1s,
    const float* __restrict__ a1d, const float* __restrict__ W2,
    const float* __restrict__ a2s, const float* __restrict__ a2d,
    float* __restrict__ out,
    float* __restrict__ h1, float* __restrict__ es1, float* __restrict__ ed1,
    float* __restrict__ h2, float* __restrict__ es2, float* __restrict__ ed2,
    int* __restrict__ deg, int* __restrict__ cols, float* __restrict__ Wt,
    int* __restrict__ bars) {
    const int bid = blockIdx.x, t = threadIdx.x;
    const int wv = t >> 6, ln = t & 63;

    __shared__ int cnt;
    __shared__ int cls[MAX_DEG];
    __shared__ float xs[4 * F_IN];                    // 8 KB
    __shared__ float pM[4][C1], pS[4][C1], pA[4][C1]; // 3 KB
    __shared__ float rowbuf[C1];

    // ---------------- Phase 0a: Wt[c][f] = W1[h][f][d], c=h*8+d ----------------
    {
        int idx = bid * 256 + t;
        if (idx < C1 * F_IN) {
            int c = idx >> 9, f = idx & 511;
            Wt[idx] = W1[((c >> 3) << 12) | (f << 3) | (c & 7)];
        }
    }
    // ---------------- Phase 0b: CSR for 4 nodes ----------------
    for (int it = 0; it < 4; ++it) {
        const int n = bid * 4 + it;
        if (t == 0) cnt = 0;
        __syncthreads();
        const float4* row4 = (const float4*)(adj + (size_t)n * NN);
#pragma unroll
        for (int i = 0; i < 4; i++) {
            float4 v = row4[i * 256 + t];
            int base = (i * 256 + t) * 4;
            if (v.x > 0.f) { int p = atomicAdd(&cnt, 1); if (p < MAX_DEG) cls[p] = base; }
            if (v.y > 0.f) { int p = atomicAdd(&cnt, 1); if (p < MAX_DEG) cls[p] = base + 1; }
            if (v.z > 0.f) { int p = atomicAdd(&cnt, 1); if (p < MAX_DEG) cls[p] = base + 2; }
            if (v.w > 0.f) { int p = atomicAdd(&cnt, 1); if (p < MAX_DEG) cls[p] = base + 3; }
        }
        __syncthreads();
        int dc = cnt < MAX_DEG ? cnt : MAX_DEG;
        if (t == 0) deg[n] = dc;
        for (int i = t; i < dc; i += 256) cols[n * MAX_DEG + i] = cls[i];
        __syncthreads();
    }
    grid_barrier(&bars[0]);

    // ---------------- Phase 1: proj1, 1 row per wave ----------------
    {
        const int n0 = bid * 4;
        const float4* x4 = (const float4*)(x + (size_t)n0 * F_IN);
        float4* xs4 = (float4*)xs;
#pragma unroll
        for (int i = 0; i < 2; i++) xs4[t + i * 256] = x4[t + i * 256];
        __syncthreads();
        const int c = ln;
        const float4* wrow = (const float4*)(Wt + c * F_IN);
        const float4* r0 = (const float4*)(xs + wv * F_IN);
        float ax = 0.f, ay = 0.f, az = 0.f, aw = 0.f;
#pragma unroll 4
        for (int q = 0; q < F_IN / 4; q++) {
            float4 w = wrow[q];
            float4 u = r0[q];
            ax += u.x * w.x; ay += u.y * w.y; az += u.z * w.z; aw += u.w * w.w;
        }
        float A = (ax + ay) + (az + aw);
        const int n = n0 + wv;
        h1[(size_t)n * C1 + c] = A;
        float vs = A * a1s[c], vd = A * a1d[c];
        vs += __shfl_xor(vs, 1, 64); vd += __shfl_xor(vd, 1, 64);
        vs += __shfl_xor(vs, 2, 64); vd += __shfl_xor(vd, 2, 64);
        vs += __shfl_xor(vs, 4, 64); vd += __shfl_xor(vd, 4, 64);
        if ((c & 7) == 0) { es1[n * HEADS + (c >> 3)] = vs; ed1[n * HEADS + (c >> 3)] = vd; }
    }
    grid_barrier(&bars[1]);

    // ---------------- Phase 2: layer-1 attn (4 waves split neighbors), ELU, W2, e2 ----------------
    for (int it = 0; it < 4; ++it) {
        const int n = bid * 4 + it;
        const int dg = deg[n];
        for (int i = t; i < dg; i += 256) cls[i] = cols[n * MAX_DEG + i];
        __syncthreads();
        const int h = ln >> 3;
        const float es = es1[n * HEADS + h];
        float M = -1e30f, S = 0.f, acc = 0.f;
        for (int j = wv; j < dg; j += 4) {
            int m = cls[j];
            float e = es + ed1[m * HEADS + h];
            e = e > 0.f ? e : LEAKY * e;
            float hv = h1[(size_t)m * C1 + ln];
            float Mn = fmaxf(M, e);
            float sc = __expf(M - Mn);
            float p = __expf(e - Mn);
            acc = acc * sc + p * hv;
            S = S * sc + p;
            M = Mn;
        }
        pM[wv][ln] = M; pS[wv][ln] = S; pA[wv][ln] = acc;
        __syncthreads();
        if (wv == 0) {
#pragma unroll
            for (int q = 1; q < 4; q++) {
                float Mo = pM[q][ln], So = pS[q][ln], ao = pA[q][ln];
                float Mn = fmaxf(M, Mo);
                float s1 = __expf(M - Mn), s2 = __expf(Mo - Mn);
                acc = acc * s1 + ao * s2;
                S = S * s1 + So * s2;
                M = Mn;
            }
            float o = acc / S;
            o = o > 0.f ? o : __expf(o) - 1.f;  // ELU
            rowbuf[ln] = o;
        }
        __syncthreads();
        if (wv == 0) {
            const int k = ln & 15, g = ln >> 4;
            float hk = 0.f;
#pragma unroll
            for (int cc = 0; cc < 16; cc++) {
                int c2 = g * 16 + cc;
                hk += rowbuf[c2] * W2[c2 * NCLASS + k];
            }
            hk += __shfl_xor(hk, 16, 64);
            hk += __shfl_xor(hk, 32, 64);
            if (ln < 16) h2[n * NCLASS + k] = hk;
            float vs = hk * a2s[k];
            float vd = hk * a2d[k];
#pragma unroll
            for (int msk = 8; msk >= 1; msk >>= 1) {
                vs += __shfl_xor(vs, msk, 64);
                vd += __shfl_xor(vd, msk, 64);
            }
            if (ln == 0) { es2[n] = vs; ed2[n] = vd; }
        }
        __syncthreads();
    }
    grid_barrier(&bars[2]);

    // ---------------- Phase 3: layer-2 attn + log_softmax, 1 node per wave ----------------
    {
        const int n = bid * 4 + wv;
        const int dg = deg[n];
        const int k = ln & 15, g = ln >> 4;
        const float es = es2[n];
        float M = -1e30f, S = 0.f, acc = 0.f;
        for (int j = g; j < dg; j += 4) {
            int m = cols[n * MAX_DEG + j];
            float e = es + ed2[m];
            e = e > 0.f ? e : LEAKY * e;
            float hv = h2[m * NCLASS + k];
            float Mn = fmaxf(M, e);
            float sc = __expf(M - Mn);
            float p = __expf(e - Mn);
            acc = acc * sc + p * hv;
            S = S * sc + p;
            M = Mn;
        }
#pragma unroll
        for (int msk = 16; msk <= 32; msk <<= 1) {
            float Mo = __shfl_xor(M, msk, 64);
            float So = __shfl_xor(S, msk, 64);
            float ao = __shfl_xor(acc, msk, 64);
            float Mn = fmaxf(M, Mo);
            float s1 = __expf(M - Mn), s2 = __expf(Mo - Mn);
            acc = acc * s1 + ao * s2;
            S = S * s1 + So * s2;
            M = Mn;
        }
        float v = acc / S;
        float mx = v;
#pragma unroll
        for (int msk = 1; msk <= 8; msk <<= 1) mx = fmaxf(mx, __shfl_xor(mx, msk, 64));
        float ex = __expf(v - mx);
        float se = ex;
#pragma unroll
        for (int msk = 1; msk <= 8; msk <<= 1) se += __shfl_xor(se, msk, 64);
        float r = v - mx - __logf(se);
        if (ln < 16) out[n * NCLASS + k] = r;
    }
}

extern "C" void kernel_launch(void* const* d_in, const int* in_sizes, int n_in,
                              void* d_out, int out_size, void* d_ws, size_t ws_size,
                              hipStream_t stream) {
    const float* x   = (const float*)d_in[0];
    const float* adj = (const float*)d_in[1];
    const float* W1  = (const float*)d_in[2];
    const float* a1s = (const float*)d_in[3];
    const float* a1d = (const float*)d_in[4];
    const float* W2  = (const float*)d_in[5];
    const float* a2s = (const float*)d_in[6];
    const float* a2d = (const float*)d_in[7];
    float* out = (float*)d_out;

    float* ws  = (float*)d_ws;
    float* h1  = ws;                  // 4096*64
    float* es1 = h1 + NN * C1;        // 4096*8
    float* ed1 = es1 + NN * HEADS;    // 4096*8
    float* h2  = ed1 + NN * HEADS;    // 4096*16
    float* es2 = h2 + NN * NCLASS;    // 4096
    float* ed2 = es2 + NN;            // 4096
    int* deg  = (int*)(ed2 + NN);     // 4096
    int* cols = deg + NN;             // 4096*MAX_DEG
    float* Wt = (float*)(cols + NN * MAX_DEG);  // 64*512
    int* bars = (int*)(Wt + C1 * F_IN);         // 8 ints

    k_init<<<1, 64, 0, stream>>>(bars);
    k_fused<<<NBLK, 256, 0, stream>>>(x, adj, W1, a1s, a1d, W2, a2s, a2d, out,
                                      h1, es1, ed1, h2, es2, ed2, deg, cols, Wt, bars);
}

// Round 10
// 339.664 us; speedup vs baseline: 1.6391x; 1.6391x over previous
//
#include <hip/hip_runtime.h>
#include <math.h>

#define NN 4096
#define F_IN 512
#define HEADS 8
#define D_HEAD 8
#define C1 64
#define NCLASS 16
#define MAX_DEG 128
#define LEAKY 0.2f
#define NBLK 1024

// Cheap device-scope grid barrier: RELAXED spin (no per-poll L2 invalidation),
// single release fence on arrival, single acquire fence on exit.
__device__ __forceinline__ void grid_barrier(int* bar) {
    __syncthreads();
    if (threadIdx.x == 0) {
        __builtin_amdgcn_fence(__ATOMIC_RELEASE, "agent");  // publish block's writes (L2 wb) once
        __hip_atomic_fetch_add(bar, 1, __ATOMIC_RELAXED, __HIP_MEMORY_SCOPE_AGENT);
        while (__hip_atomic_load(bar, __ATOMIC_RELAXED, __HIP_MEMORY_SCOPE_AGENT) < NBLK)
            __builtin_amdgcn_s_sleep(8);                    // ~512 cy between polls
        __builtin_amdgcn_fence(__ATOMIC_ACQUIRE, "agent");  // invalidate stale cache once
    }
    __syncthreads();
}

__global__ __launch_bounds__(64) void k_init(int* __restrict__ bars) {
    if (threadIdx.x < 8) bars[threadIdx.x] = 0;
}

// One fused kernel, 1024 blocks x 256 threads (4 blocks/CU -> all 1024 co-resident).
// Phase A (no cross-block deps): CSR build (4 adj rows/block) + proj1 (4 rows/block,
//          W1 read directly, 4-wave cooperative f-split, LDS partial reduce)
// barrier0
// Phase B: layer-1 attention + ELU + W2 proj + e2 dots (4 nodes/block)
// barrier1
// Phase C: layer-2 attention + log_softmax (1 node/wave)
__global__ __launch_bounds__(256, 4) void k_fused(
    const float* __restrict__ x, const float* __restrict__ adj,
    const float* __restrict__ W1, const float* __restrict__ a1s,
    const float* __restrict__ a1d, const float* __restrict__ W2,
    const float* __restrict__ a2s, const float* __restrict__ a2d,
    float* __restrict__ out,
    float* __restrict__ h1, float* __restrict__ es1, float* __restrict__ ed1,
    float* __restrict__ h2, float* __restrict__ es2, float* __restrict__ ed2,
    int* __restrict__ deg, int* __restrict__ cols, int* __restrict__ bars) {
    const int bid = blockIdx.x, t = threadIdx.x;
    const int wv = t >> 6, ln = t & 63;

    __shared__ int cnt;
    __shared__ int cls[MAX_DEG];
    __shared__ float xs[4 * F_IN];                    // 8 KB
    __shared__ float pAcc[4][4][C1];                  // 4 KB  (wave partials: [wv][row][c])
    __shared__ float pM[4][C1], pS[4][C1], pA[4][C1]; // 3 KB
    __shared__ float rowbuf[C1];

    // ---------------- Phase A1: CSR for 4 nodes ----------------
    for (int it = 0; it < 4; ++it) {
        const int n = bid * 4 + it;
        if (t == 0) cnt = 0;
        __syncthreads();
        const float4* row4 = (const float4*)(adj + (size_t)n * NN);
#pragma unroll
        for (int i = 0; i < 4; i++) {
            float4 v = row4[i * 256 + t];
            int base = (i * 256 + t) * 4;
            if (v.x > 0.f) { int p = atomicAdd(&cnt, 1); if (p < MAX_DEG) cls[p] = base; }
            if (v.y > 0.f) { int p = atomicAdd(&cnt, 1); if (p < MAX_DEG) cls[p] = base + 1; }
            if (v.z > 0.f) { int p = atomicAdd(&cnt, 1); if (p < MAX_DEG) cls[p] = base + 2; }
            if (v.w > 0.f) { int p = atomicAdd(&cnt, 1); if (p < MAX_DEG) cls[p] = base + 3; }
        }
        __syncthreads();
        int dc = cnt < MAX_DEG ? cnt : MAX_DEG;
        if (t == 0) deg[n] = dc;
        for (int i = t; i < dc; i += 256) cols[n * MAX_DEG + i] = cls[i];
        __syncthreads();
    }

    // ---------------- Phase A2: proj1, 4-wave cooperative over f ----------------
    {
        const int n0 = bid * 4;
        const float4* x4 = (const float4*)(x + (size_t)n0 * F_IN);
        float4* xs4 = (float4*)xs;
#pragma unroll
        for (int i = 0; i < 2; i++) xs4[t + i * 256] = x4[t + i * 256];
        __syncthreads();
        const int c = ln;
        // W1[h][f][d] read directly: lane c -> W1[(c>>3)<<12 | f<<3 | (c&7)]
        const float* wbase = W1 + ((c >> 3) << 12) + (c & 7);
        float a0 = 0.f, a1 = 0.f, a2 = 0.f, a3 = 0.f;
        const int f0 = wv * 128;
#pragma unroll 8
        for (int ff = 0; ff < 128; ff++) {
            const int f = f0 + ff;
            float w = wbase[f << 3];
            a0 += xs[0 * F_IN + f] * w;
            a1 += xs[1 * F_IN + f] * w;
            a2 += xs[2 * F_IN + f] * w;
            a3 += xs[3 * F_IN + f] * w;
        }
        pAcc[wv][0][c] = a0; pAcc[wv][1][c] = a1;
        pAcc[wv][2][c] = a2; pAcc[wv][3][c] = a3;
        __syncthreads();
        // wave wv reduces + finishes row n0+wv
        float A = (pAcc[0][wv][c] + pAcc[1][wv][c]) + (pAcc[2][wv][c] + pAcc[3][wv][c]);
        const int n = n0 + wv;
        h1[(size_t)n * C1 + c] = A;
        float vs = A * a1s[c], vd = A * a1d[c];
        vs += __shfl_xor(vs, 1, 64); vd += __shfl_xor(vd, 1, 64);
        vs += __shfl_xor(vs, 2, 64); vd += __shfl_xor(vd, 2, 64);
        vs += __shfl_xor(vs, 4, 64); vd += __shfl_xor(vd, 4, 64);
        if ((c & 7) == 0) { es1[n * HEADS + (c >> 3)] = vs; ed1[n * HEADS + (c >> 3)] = vd; }
    }
    grid_barrier(&bars[0]);

    // ---------------- Phase B: layer-1 attn (4 waves split neighbors), ELU, W2, e2 ----------------
    for (int it = 0; it < 4; ++it) {
        const int n = bid * 4 + it;
        const int dg = deg[n];
        for (int i = t; i < dg; i += 256) cls[i] = cols[n * MAX_DEG + i];
        __syncthreads();
        const int h = ln >> 3;
        const float es = es1[n * HEADS + h];
        float M = -1e30f, S = 0.f, acc = 0.f;
        for (int j = wv; j < dg; j += 4) {
            int m = cls[j];
            float e = es + ed1[m * HEADS + h];
            e = e > 0.f ? e : LEAKY * e;
            float hv = h1[(size_t)m * C1 + ln];
            float Mn = fmaxf(M, e);
            float sc = __expf(M - Mn);
            float p = __expf(e - Mn);
            acc = acc * sc + p * hv;
            S = S * sc + p;
            M = Mn;
        }
        pM[wv][ln] = M; pS[wv][ln] = S; pA[wv][ln] = acc;
        __syncthreads();
        if (wv == 0) {
#pragma unroll
            for (int q = 1; q < 4; q++) {
                float Mo = pM[q][ln], So = pS[q][ln], ao = pA[q][ln];
                float Mn = fmaxf(M, Mo);
                float s1 = __expf(M - Mn), s2 = __expf(Mo - Mn);
                acc = acc * s1 + ao * s2;
                S = S * s1 + So * s2;
                M = Mn;
            }
            float o = acc / S;
            o = o > 0.f ? o : __expf(o) - 1.f;  // ELU
            rowbuf[ln] = o;
        }
        __syncthreads();
        if (wv == 0) {
            const int k = ln & 15, g = ln >> 4;
            float hk = 0.f;
#pragma unroll
            for (int cc = 0; cc < 16; cc++) {
                int c2 = g * 16 + cc;
                hk += rowbuf[c2] * W2[c2 * NCLASS + k];
            }
            hk += __shfl_xor(hk, 16, 64);
            hk += __shfl_xor(hk, 32, 64);
            if (ln < 16) h2[n * NCLASS + k] = hk;
            float vs = hk * a2s[k];
            float vd = hk * a2d[k];
#pragma unroll
            for (int msk = 8; msk >= 1; msk >>= 1) {
                vs += __shfl_xor(vs, msk, 64);
                vd += __shfl_xor(vd, msk, 64);
            }
            if (ln == 0) { es2[n] = vs; ed2[n] = vd; }
        }
        __syncthreads();
    }
    grid_barrier(&bars[1]);

    // ---------------- Phase C: layer-2 attn + log_softmax, 1 node per wave ----------------
    {
        const int n = bid * 4 + wv;
        const int dg = deg[n];
        const int k = ln & 15, g = ln >> 4;
        const float es = es2[n];
        float M = -1e30f, S = 0.f, acc = 0.f;
        for (int j = g; j < dg; j += 4) {
            int m = cols[n * MAX_DEG + j];
            float e = es + ed2[m];
            e = e > 0.f ? e : LEAKY * e;
            float hv = h2[m * NCLASS + k];
            float Mn = fmaxf(M, e);
            float sc = __expf(M - Mn);
            float p = __expf(e - Mn);
            acc = acc * sc + p * hv;
            S = S * sc + p;
            M = Mn;
        }
#pragma unroll
        for (int msk = 16; msk <= 32; msk <<= 1) {
            float Mo = __shfl_xor(M, msk, 64);
            float So = __shfl_xor(S, msk, 64);
            float ao = __shfl_xor(acc, msk, 64);
            float Mn = fmaxf(M, Mo);
            float s1 = __expf(M - Mn), s2 = __expf(Mo - Mn);
            acc = acc * s1 + ao * s2;
            S = S * s1 + So * s2;
            M = Mn;
        }
        float v = acc / S;
        float mx = v;
#pragma unroll
        for (int msk = 1; msk <= 8; msk <<= 1) mx = fmaxf(mx, __shfl_xor(mx, msk, 64));
        float ex = __expf(v - mx);
        float se = ex;
#pragma unroll
        for (int msk = 1; msk <= 8; msk <<= 1) se += __shfl_xor(se, msk, 64);
        float r = v - mx - __logf(se);
        if (ln < 16) out[n * NCLASS + k] = r;
    }
}

extern "C" void kernel_launch(void* const* d_in, const int* in_sizes, int n_in,
                              void* d_out, int out_size, void* d_ws, size_t ws_size,
                              hipStream_t stream) {
    const float* x   = (const float*)d_in[0];
    const float* adj = (const float*)d_in[1];
    const float* W1  = (const float*)d_in[2];
    const float* a1s = (const float*)d_in[3];
    const float* a1d = (const float*)d_in[4];
    const float* W2  = (const float*)d_in[5];
    const float* a2s = (const float*)d_in[6];
    const float* a2d = (const float*)d_in[7];
    float* out = (float*)d_out;

    float* ws  = (float*)d_ws;
    float* h1  = ws;                  // 4096*64
    float* es1 = h1 + NN * C1;        // 4096*8
    float* ed1 = es1 + NN * HEADS;    // 4096*8
    float* h2  = ed1 + NN * HEADS;    // 4096*16
    float* es2 = h2 + NN * NCLASS;    // 4096
    float* ed2 = es2 + NN;            // 4096
    int* deg  = (int*)(ed2 + NN);     // 4096
    int* cols = deg + NN;             // 4096*MAX_DEG
    int* bars = cols + NN * MAX_DEG;  // 8 ints

    k_init<<<1, 64, 0, stream>>>(bars);
    k_fused<<<NBLK, 256, 0, stream>>>(x, adj, W1, a1s, a1d, W2, a2s, a2d, out,
                                      h1, es1, ed1, h2, es2, ed2, deg, cols, bars);
}

// Round 12
// 187.252 us; speedup vs baseline: 2.9733x; 1.8139x over previous
//
#include <hip/hip_runtime.h>
#include <math.h>

#define NN 4096
#define F_IN 512
#define HEADS 8
#define D_HEAD 8
#define C1 64
#define NCLASS 16
#define MAX_DEG 128
#define LEAKY 0.2f
#define NBLK 1024
#define NGRP 64          // 64 groups x 16 blocks
#define GRP_SZ 16
#define BAR_STRIDE 8256  // per-barrier int footprint: 64*64 cnt + 64 root + 64*64 go

// Two-level grid barrier: per-group arrival counters (padded lines), root counter,
// per-group go flags. Only 16 pollers per line -> no coherence-point queueing.
__device__ __forceinline__ void grid_barrier(int* bars, int b, int grp, int wv, int ln) {
    __syncthreads();
    if (wv == 0) {
        int* base = bars + b * BAR_STRIDE;
        int* grp_cnt = base;            // stride 64 ints
        int* root    = base + 4096;
        int* go      = base + 4160;     // stride 64 ints
        int lr = 0;
        if (ln == 0) {
            __builtin_amdgcn_fence(__ATOMIC_RELEASE, "agent");  // publish this block's writes
            int a = __hip_atomic_fetch_add(&grp_cnt[grp << 6], 1, __ATOMIC_RELAXED,
                                           __HIP_MEMORY_SCOPE_AGENT);
            if (a == GRP_SZ - 1) {      // last block of group
                int r = __hip_atomic_fetch_add(root, 1, __ATOMIC_RELAXED,
                                               __HIP_MEMORY_SCOPE_AGENT);
                lr = (r == NGRP - 1);   // last group overall
            }
        }
        lr = __shfl(lr, 0, 64);
        if (lr)                          // 64 lanes release 64 group flags at once
            __hip_atomic_store(&go[ln << 6], 1, __ATOMIC_RELAXED, __HIP_MEMORY_SCOPE_AGENT);
        if (ln == 0) {
            while (__hip_atomic_load(&go[grp << 6], __ATOMIC_RELAXED,
                                     __HIP_MEMORY_SCOPE_AGENT) == 0)
                __builtin_amdgcn_s_sleep(16);                   // ~1k cycles between polls
            __builtin_amdgcn_fence(__ATOMIC_ACQUIRE, "agent");  // invalidate stale caches once
        }
    }
    __syncthreads();
}

__global__ __launch_bounds__(1024) void k_init(int* __restrict__ bars) {
    int i = blockIdx.x * 1024 + threadIdx.x;
    if (i < 2 * BAR_STRIDE) bars[i] = 0;
}

// One fused kernel, 1024 blocks x 256 threads (4 blocks/CU -> all 1024 co-resident).
// Phase A: CSR build (4 adj rows/block) + proj1 (W1 direct, 4-wave f-split)
// barrier0 | Phase B: layer-1 attn + ELU + W2 proj + e2 dots (4 nodes/block)
// barrier1 | Phase C: layer-2 attn + log_softmax (1 node/wave)
__global__ __launch_bounds__(256, 4) void k_fused(
    const float* __restrict__ x, const float* __restrict__ adj,
    const float* __restrict__ W1, const float* __restrict__ a1s,
    const float* __restrict__ a1d, const float* __restrict__ W2,
    const float* __restrict__ a2s, const float* __restrict__ a2d,
    float* __restrict__ out,
    float* __restrict__ h1, float* __restrict__ es1, float* __restrict__ ed1,
    float* __restrict__ h2, float* __restrict__ es2, float* __restrict__ ed2,
    int* __restrict__ deg, int* __restrict__ cols, int* __restrict__ bars) {
    const int bid = blockIdx.x, t = threadIdx.x;
    const int wv = t >> 6, ln = t & 63;
    const int grp = bid >> 4;

    __shared__ int cnt;
    __shared__ int cls[MAX_DEG];
    __shared__ float xs[4 * F_IN];                    // 8 KB
    __shared__ float pAcc[4][4][C1];                  // 4 KB
    __shared__ float pM[4][C1], pS[4][C1], pA[4][C1]; // 3 KB
    __shared__ float rowbuf[C1];

    // ---------------- Phase A1: CSR for 4 nodes ----------------
    for (int it = 0; it < 4; ++it) {
        const int n = bid * 4 + it;
        if (t == 0) cnt = 0;
        __syncthreads();
        const float4* row4 = (const float4*)(adj + (size_t)n * NN);
#pragma unroll
        for (int i = 0; i < 4; i++) {
            float4 v = row4[i * 256 + t];
            int base = (i * 256 + t) * 4;
            if (v.x > 0.f) { int p = atomicAdd(&cnt, 1); if (p < MAX_DEG) cls[p] = base; }
            if (v.y > 0.f) { int p = atomicAdd(&cnt, 1); if (p < MAX_DEG) cls[p] = base + 1; }
            if (v.z > 0.f) { int p = atomicAdd(&cnt, 1); if (p < MAX_DEG) cls[p] = base + 2; }
            if (v.w > 0.f) { int p = atomicAdd(&cnt, 1); if (p < MAX_DEG) cls[p] = base + 3; }
        }
        __syncthreads();
        int dc = cnt < MAX_DEG ? cnt : MAX_DEG;
        if (t == 0) deg[n] = dc;
        for (int i = t; i < dc; i += 256) cols[n * MAX_DEG + i] = cls[i];
        __syncthreads();
    }

    // ---------------- Phase A2: proj1, 4-wave cooperative over f ----------------
    {
        const int n0 = bid * 4;
        const float4* x4 = (const float4*)(x + (size_t)n0 * F_IN);
        float4* xs4 = (float4*)xs;
#pragma unroll
        for (int i = 0; i < 2; i++) xs4[t + i * 256] = x4[t + i * 256];
        __syncthreads();
        const int c = ln;
        const float* wbase = W1 + ((c >> 3) << 12) + (c & 7);
        float a0 = 0.f, a1 = 0.f, a2 = 0.f, a3 = 0.f;
        const int f0 = wv * 128;
#pragma unroll 8
        for (int ff = 0; ff < 128; ff++) {
            const int f = f0 + ff;
            float w = wbase[f << 3];
            a0 += xs[0 * F_IN + f] * w;
            a1 += xs[1 * F_IN + f] * w;
            a2 += xs[2 * F_IN + f] * w;
            a3 += xs[3 * F_IN + f] * w;
        }
        pAcc[wv][0][c] = a0; pAcc[wv][1][c] = a1;
        pAcc[wv][2][c] = a2; pAcc[wv][3][c] = a3;
        __syncthreads();
        float A = (pAcc[0][wv][c] + pAcc[1][wv][c]) + (pAcc[2][wv][c] + pAcc[3][wv][c]);
        const int n = n0 + wv;
        h1[(size_t)n * C1 + c] = A;
        float vs = A * a1s[c], vd = A * a1d[c];
        vs += __shfl_xor(vs, 1, 64); vd += __shfl_xor(vd, 1, 64);
        vs += __shfl_xor(vs, 2, 64); vd += __shfl_xor(vd, 2, 64);
        vs += __shfl_xor(vs, 4, 64); vd += __shfl_xor(vd, 4, 64);
        if ((c & 7) == 0) { es1[n * HEADS + (c >> 3)] = vs; ed1[n * HEADS + (c >> 3)] = vd; }
    }
    grid_barrier(bars, 0, grp, wv, ln);

    // ---------------- Phase B: layer-1 attn (4 waves split neighbors), ELU, W2, e2 ----------------
    for (int it = 0; it < 4; ++it) {
        const int n = bid * 4 + it;
        const int dg = deg[n];
        for (int i = t; i < dg; i += 256) cls[i] = cols[n * MAX_DEG + i];
        __syncthreads();
        const int h = ln >> 3;
        const float es = es1[n * HEADS + h];
        float M = -1e30f, S = 0.f, acc = 0.f;
        for (int j = wv; j < dg; j += 4) {
            int m = cls[j];
            float e = es + ed1[m * HEADS + h];
            e = e > 0.f ? e : LEAKY * e;
            float hv = h1[(size_t)m * C1 + ln];
            float Mn = fmaxf(M, e);
            float sc = __expf(M - Mn);
            float p = __expf(e - Mn);
            acc = acc * sc + p * hv;
            S = S * sc + p;
            M = Mn;
        }
        pM[wv][ln] = M; pS[wv][ln] = S; pA[wv][ln] = acc;
        __syncthreads();
        if (wv == 0) {
#pragma unroll
            for (int q = 1; q < 4; q++) {
                float Mo = pM[q][ln], So = pS[q][ln], ao = pA[q][ln];
                float Mn = fmaxf(M, Mo);
                float s1 = __expf(M - Mn), s2 = __expf(Mo - Mn);
                acc = acc * s1 + ao * s2;
                S = S * s1 + So * s2;
                M = Mn;
            }
            float o = acc / S;
            o = o > 0.f ? o : __expf(o) - 1.f;  // ELU
            rowbuf[ln] = o;
        }
        __syncthreads();
        if (wv == 0) {
            const int k = ln & 15, g = ln >> 4;
            float hk = 0.f;
#pragma unroll
            for (int cc = 0; cc < 16; cc++) {
                int c2 = g * 16 + cc;
                hk += rowbuf[c2] * W2[c2 * NCLASS + k];
            }
            hk += __shfl_xor(hk, 16, 64);
            hk += __shfl_xor(hk, 32, 64);
            if (ln < 16) h2[n * NCLASS + k] = hk;
            float vs = hk * a2s[k];
            float vd = hk * a2d[k];
#pragma unroll
            for (int msk = 8; msk >= 1; msk >>= 1) {
                vs += __shfl_xor(vs, msk, 64);
                vd += __shfl_xor(vd, msk, 64);
            }
            if (ln == 0) { es2[n] = vs; ed2[n] = vd; }
        }
        __syncthreads();
    }
    grid_barrier(bars, 1, grp, wv, ln);

    // ---------------- Phase C: layer-2 attn + log_softmax, 1 node per wave ----------------
    {
        const int n = bid * 4 + wv;
        const int dg = deg[n];
        const int k = ln & 15, g = ln >> 4;
        const float es = es2[n];
        float M = -1e30f, S = 0.f, acc = 0.f;
        for (int j = g; j < dg; j += 4) {
            int m = cols[n * MAX_DEG + j];
            float e = es + ed2[m];
            e = e > 0.f ? e : LEAKY * e;
            float hv = h2[m * NCLASS + k];
            float Mn = fmaxf(M, e);
            float sc = __expf(M - Mn);
            float p = __expf(e - Mn);
            acc = acc * sc + p * hv;
            S = S * sc + p;
            M = Mn;
        }
#pragma unroll
        for (int msk = 16; msk <= 32; msk <<= 1) {
            float Mo = __shfl_xor(M, msk, 64);
            float So = __shfl_xor(S, msk, 64);
            float ao = __shfl_xor(acc, msk, 64);
            float Mn = fmaxf(M, Mo);
            float s1 = __expf(M - Mn), s2 = __expf(Mo - Mn);
            acc = acc * s1 + ao * s2;
            S = S * s1 + So * s2;
            M = Mn;
        }
        float v = acc / S;
        float mx = v;
#pragma unroll
        for (int msk = 1; msk <= 8; msk <<= 1) mx = fmaxf(mx, __shfl_xor(mx, msk, 64));
        float ex = __expf(v - mx);
        float se = ex;
#pragma unroll
        for (int msk = 1; msk <= 8; msk <<= 1) se += __shfl_xor(se, msk, 64);
        float r = v - mx - __logf(se);
        if (ln < 16) out[n * NCLASS + k] = r;
    }
}

extern "C" void kernel_launch(void* const* d_in, const int* in_sizes, int n_in,
                              void* d_out, int out_size, void* d_ws, size_t ws_size,
                              hipStream_t stream) {
    const float* x   = (const float*)d_in[0];
    const float* adj = (const float*)d_in[1];
    const float* W1  = (const float*)d_in[2];
    const float* a1s = (const float*)d_in[3];
    const float* a1d = (const float*)d_in[4];
    const float* W2  = (const float*)d_in[5];
    const float* a2s = (const float*)d_in[6];
    const float* a2d = (const float*)d_in[7];
    float* out = (float*)d_out;

    float* ws  = (float*)d_ws;
    float* h1  = ws;                  // 4096*64
    float* es1 = h1 + NN * C1;        // 4096*8
    float* ed1 = es1 + NN * HEADS;    // 4096*8
    float* h2  = ed1 + NN * HEADS;    // 4096*16
    float* es2 = h2 + NN * NCLASS;    // 4096
    float* ed2 = es2 + NN;            // 4096
    int* deg  = (int*)(ed2 + NN);     // 4096
    int* cols = deg + NN;             // 4096*MAX_DEG
    int* bars = cols + NN * MAX_DEG;  // 2*8256 ints

    k_init<<<17, 1024, 0, stream>>>(bars);
    k_fused<<<NBLK, 256, 0, stream>>>(x, adj, W1, a1s, a1d, W2, a2s, a2d, out,
                                      h1, es1, ed1, h2, es2, ed2, deg, cols, bars);
}